// Round 6
// baseline (737.242 us; speedup 1.0000x reference)
//
#include <hip/hip_runtime.h>
#include <stdint.h>

// Full Walsh-Hadamard transform, length 2^20, on 16 rows (B=16).
// Fused single-kernel producer-consumer:
//   - 4096 blocks; block b produces pass1 chunk b (strides 2^0..2^11 within a
//     contiguous 4096-float chunk), stores bf16 to ws, then release-increments
//     a per-row counter.
//   - Blocks with (b&255)<64 additionally consume: after acquire-spinning on
//     their OWN row's counter (staggered => spin ~= one row tail), they run
//     pass2 (WHT-256 over h=idx>>12) on tile (row, pb) and write f32 out.
// Scale: inv_sqrt2^20 = 2^-10 exact; split 2^-6 (pass1) * 2^-4 (pass2).
// Counters live past 32MB in d_ws, zeroed per call via hipMemsetAsync
// (graph-capture-legal, replay-safe). Fallback: 2-kernel f32 path.

typedef float f32x4_t __attribute__((ext_vector_type(4)));

__device__ __forceinline__ float bf16lo_to_f32(uint32_t u) {
    return __builtin_bit_cast(float, u << 16);
}
__device__ __forceinline__ float bf16hi_to_f32(uint32_t u) {
    return __builtin_bit_cast(float, u & 0xFFFF0000u);
}
__device__ __forceinline__ uint32_t rne_bf16bits(float x) {
    uint32_t b = __builtin_bit_cast(uint32_t, x);
    b += 0x7FFFu + ((b >> 16) & 1u);
    return b >> 16;
}
__device__ __forceinline__ uint32_t pack_bf16x2(float lo, float hi) {
    uint32_t bl = __builtin_bit_cast(uint32_t, lo);
    bl += 0x7FFFu + ((bl >> 16) & 1u);
    uint32_t bh = __builtin_bit_cast(uint32_t, hi);
    bh += 0x7FFFu + ((bh >> 16) & 1u);
    return (bl >> 16) | (bh & 0xFFFF0000u);
}

__device__ __forceinline__ void bfly16_all(float v[16]) {
    #pragma unroll
    for (int bit = 1; bit <= 8; bit <<= 1) {
        #pragma unroll
        for (int m = 0; m < 16; ++m) {
            if (!(m & bit)) {
                float a = v[m], b = v[m | bit];
                v[m] = a + b;
                v[m | bit] = a - b;
            }
        }
    }
}

__device__ __forceinline__ void bfly16_all4(float4 v[16]) {
    #pragma unroll
    for (int bit = 1; bit <= 8; bit <<= 1) {
        #pragma unroll
        for (int m = 0; m < 16; ++m) {
            if (!(m & bit)) {
                float4 a = v[m], b = v[m | bit];
                v[m].x = a.x + b.x; v[m].y = a.y + b.y;
                v[m].z = a.z + b.z; v[m].w = a.w + b.w;
                v[m | bit].x = a.x - b.x; v[m | bit].y = a.y - b.y;
                v[m | bit].z = a.z - b.z; v[m | bit].w = a.w - b.w;
            }
        }
    }
}

// pad: +4 floats every 64 to break the bits{0..4}-only bank aliasing
__device__ __forceinline__ int padA(int l) { return l + ((l >> 6) << 2); }

// ---------------- Fused kernel ----------------
__global__ __launch_bounds__(256) void wht_fused(const float* __restrict__ x,
                                                 uint16_t* __restrict__ ws,
                                                 uint32_t* __restrict__ cnt,
                                                 float* __restrict__ out) {
    __shared__ __align__(16) char smem[32768];   // pass1: 17408 B f32; pass2: 32768 B uint2
    const int t = threadIdx.x;
    const int b = blockIdx.x;

    // ======== PRODUCE: pass1 chunk b ========
    {
        float* lds = reinterpret_cast<float*>(smem);
        const size_t base = (size_t)b << 12;

        float v[16];
        // Phase A: l = 4t + j + 1024*k4 -> strides {1,2,1024,2048}
        #pragma unroll
        for (int k4 = 0; k4 < 4; ++k4) {
            float4 f = reinterpret_cast<const float4*>(x + base)[t + 256 * k4];
            v[k4 * 4 + 0] = f.x; v[k4 * 4 + 1] = f.y;
            v[k4 * 4 + 2] = f.z; v[k4 * 4 + 3] = f.w;
        }
        bfly16_all(v);
        #pragma unroll
        for (int k4 = 0; k4 < 4; ++k4) {
            int l = 4 * t + 1024 * k4;
            *reinterpret_cast<float4*>(&lds[padA(l)]) =
                make_float4(v[k4 * 4 + 0], v[k4 * 4 + 1], v[k4 * 4 + 2], v[k4 * 4 + 3]);
        }
        __syncthreads();

        // Phase B: l = (t&3) + 4m + 64*(t>>2) -> strides {4,8,16,32}
        const int cB = (t & 3) + 64 * (t >> 2);
        #pragma unroll
        for (int m = 0; m < 16; ++m) v[m] = lds[padA(cB + 4 * m)];
        bfly16_all(v);
        #pragma unroll
        for (int m = 0; m < 16; ++m) lds[padA(cB + 4 * m)] = v[m];
        __syncthreads();

        // Phase C: l = (t&63) + 64m + 1024*(t>>6) -> strides {64,128,256,512}
        const int cC = (t & 63) + 1024 * (t >> 6);
        #pragma unroll
        for (int m = 0; m < 16; ++m) v[m] = lds[padA(cC + 64 * m)];
        bfly16_all(v);

        // Repack bf16 via LDS -> 2x uint4 coalesced stores
        __syncthreads();
        uint16_t* lds16 = reinterpret_cast<uint16_t*>(smem);
        #pragma unroll
        for (int m = 0; m < 16; ++m)
            lds16[cC + 64 * m] = (uint16_t)rne_bf16bits(v[m] * 0.015625f);   // 2^-6
        __syncthreads();
        const uint4* l4 = reinterpret_cast<const uint4*>(lds16);
        uint4 a = l4[t];
        uint4 bq = l4[t + 256];
        uint4* w4 = reinterpret_cast<uint4*>(ws + base);
        w4[t] = a;
        w4[t + 256] = bq;
    }

    // Publish: all ws stores visible device-wide before counting this chunk.
    __threadfence();
    __syncthreads();
    if (t == 0)
        __hip_atomic_fetch_add(&cnt[b >> 8], 1u, __ATOMIC_RELEASE,
                               __HIP_MEMORY_SCOPE_AGENT);

    // ======== CONSUME: pass2 tile, only first 64 blocks of each row range ========
    if ((b & 255) >= 64) return;
    const int r = b >> 8;        // consumer's own row: spin ~= this row's tail
    const int pb = b & 63;

    if (t == 0) {
        while (__hip_atomic_load(&cnt[r], __ATOMIC_ACQUIRE,
                                 __HIP_MEMORY_SCOPE_AGENT) < 256u)
            __builtin_amdgcn_s_sleep(2);
    }
    __syncthreads();
    __threadfence();             // order/invalidate before cross-XCD ws reads

    {
        uint2* lds = reinterpret_cast<uint2*>(smem);   // [256 h][16 pi4], XOR swizzled
        const int pi4 = t & 15;
        const int hc = t >> 4;
        const size_t rbase = ((size_t)r << 20) + (size_t)pb * 64 + (size_t)pi4 * 4;

        float4 v[16];
        // Phase A: h = hc + 16m -> element strides 2^16..2^19
        #pragma unroll
        for (int m = 0; m < 16; ++m) {
            uint2 u = *reinterpret_cast<const uint2*>(ws + rbase + (size_t)(hc + 16 * m) * 4096);
            v[m] = make_float4(bf16lo_to_f32(u.x), bf16hi_to_f32(u.x),
                               bf16lo_to_f32(u.y), bf16hi_to_f32(u.y));
        }
        bfly16_all4(v);
        #pragma unroll
        for (int m = 0; m < 16; ++m) {
            int h = hc + 16 * m;
            lds[h * 16 + (pi4 ^ (h & 15))] =
                make_uint2(pack_bf16x2(v[m].x, v[m].y), pack_bf16x2(v[m].z, v[m].w));
        }
        __syncthreads();

        // Phase B: h = hc*16 + m -> element strides 2^12..2^15
        #pragma unroll
        for (int m = 0; m < 16; ++m) {
            int h = hc * 16 + m;
            uint2 u = lds[h * 16 + (pi4 ^ (h & 15))];
            v[m] = make_float4(bf16lo_to_f32(u.x), bf16hi_to_f32(u.x),
                               bf16lo_to_f32(u.y), bf16hi_to_f32(u.y));
        }
        bfly16_all4(v);
        #pragma unroll
        for (int m = 0; m < 16; ++m) {
            float4 o = make_float4(v[m].x * 0.0625f, v[m].y * 0.0625f,
                                   v[m].z * 0.0625f, v[m].w * 0.0625f);   // 2^-4
            *reinterpret_cast<float4*>(out + rbase + (size_t)(hc * 16 + m) * 4096) = o;
        }
    }
}

// ---------------- Fallback: original two-kernel f32 path ----------------
__global__ __launch_bounds__(256) void wht_pass1_f32(const float* __restrict__ x,
                                                     float* __restrict__ outf) {
    __shared__ float lds[4096 + 256];
    const int t = threadIdx.x;
    const size_t base = (size_t)blockIdx.x << 12;

    float v[16];
    #pragma unroll
    for (int k4 = 0; k4 < 4; ++k4) {
        float4 f = reinterpret_cast<const float4*>(x + base)[t + 256 * k4];
        v[k4 * 4 + 0] = f.x; v[k4 * 4 + 1] = f.y;
        v[k4 * 4 + 2] = f.z; v[k4 * 4 + 3] = f.w;
    }
    bfly16_all(v);
    #pragma unroll
    for (int k4 = 0; k4 < 4; ++k4) {
        int l = 4 * t + 1024 * k4;
        *reinterpret_cast<float4*>(&lds[padA(l)]) =
            make_float4(v[k4 * 4 + 0], v[k4 * 4 + 1], v[k4 * 4 + 2], v[k4 * 4 + 3]);
    }
    __syncthreads();
    const int cB = (t & 3) + 64 * (t >> 2);
    #pragma unroll
    for (int m = 0; m < 16; ++m) v[m] = lds[padA(cB + 4 * m)];
    bfly16_all(v);
    #pragma unroll
    for (int m = 0; m < 16; ++m) lds[padA(cB + 4 * m)] = v[m];
    __syncthreads();
    const int cC = (t & 63) + 1024 * (t >> 6);
    #pragma unroll
    for (int m = 0; m < 16; ++m) v[m] = lds[padA(cC + 64 * m)];
    bfly16_all(v);
    #pragma unroll
    for (int m = 0; m < 16; ++m)
        outf[base + cC + 64 * m] = v[m] * 0.015625f;
}

__global__ __launch_bounds__(256) void wht_pass2_f32(float* __restrict__ y) {
    __shared__ float4 lds[256 * 16];
    const int t = threadIdx.x;
    const int pi4 = t & 15;
    const int hc = t >> 4;
    const int pb = blockIdx.x & 63;
    const int r = blockIdx.x >> 6;
    const size_t rbase = ((size_t)r << 20) + (size_t)pb * 64 + (size_t)pi4 * 4;

    float4 v[16];
    #pragma unroll
    for (int m = 0; m < 16; ++m)
        v[m] = *reinterpret_cast<const float4*>(y + rbase + (size_t)(hc + 16 * m) * 4096);
    bfly16_all4(v);
    #pragma unroll
    for (int m = 0; m < 16; ++m) {
        int h = hc + 16 * m;
        lds[h * 16 + (pi4 ^ (h & 15))] = v[m];
    }
    __syncthreads();
    #pragma unroll
    for (int m = 0; m < 16; ++m) {
        int h = hc * 16 + m;
        v[m] = lds[h * 16 + (pi4 ^ (h & 15))];
    }
    bfly16_all4(v);
    #pragma unroll
    for (int m = 0; m < 16; ++m) {
        float4 o = make_float4(v[m].x * 0.0625f, v[m].y * 0.0625f,
                               v[m].z * 0.0625f, v[m].w * 0.0625f);
        *reinterpret_cast<float4*>(y + rbase + (size_t)(hc * 16 + m) * 4096) = o;
    }
}

extern "C" void kernel_launch(void* const* d_in, const int* in_sizes, int n_in,
                              void* d_out, int out_size, void* d_ws, size_t ws_size,
                              hipStream_t stream) {
    const float* x = (const float*)d_in[0];
    // d_in[1] (signs) and d_in[2] (indxs) are recomputed implicitly -- never read.
    float* out = (float*)d_out;

    const size_t ws_data = (size_t)16 * (1u << 20) * sizeof(uint16_t);  // 32 MB
    const size_t need_ws = ws_data + 64;                                 // + row counters
    if (ws_size >= need_ws) {
        uint16_t* ws = (uint16_t*)d_ws;
        uint32_t* cnt = (uint32_t*)((char*)d_ws + ws_data);
        hipMemsetAsync(cnt, 0, 16 * sizeof(uint32_t), stream);  // replay-safe reset
        wht_fused<<<4096, 256, 0, stream>>>(x, ws, cnt, out);
    } else {
        wht_pass1_f32<<<4096, 256, 0, stream>>>(x, out);
        wht_pass2_f32<<<1024, 256, 0, stream>>>(out);
    }
}

// Round 7
// 40.274 us; speedup vs baseline: 18.3055x; 18.3055x over previous
//
#include <hip/hip_runtime.h>
#include <stdint.h>

// Full Walsh-Hadamard transform, length 2^20, on 16 rows.
// Scale: inv_sqrt2^20 = 2^-10 exactly; split 2^-6 (pass1) * 2^-4 (pass2).
// Two kernels (fused producer-consumer variant regressed 20x in R6: agent-scope
// acquire spin-loads storm the L2s -- do not re-attempt without relaxed spins).
// Intermediate bf16 in d_ws. Pass2 tile 256h x 128p: uint4 reads (256B/16-lane
// segments), 64KB XOR-swizzled LDS exchange, 2x float4 out-stores.
// Fallback to f32 in-place path if ws_size < 32MB.

__device__ __forceinline__ float bf16lo_to_f32(uint32_t u) {
    return __builtin_bit_cast(float, u << 16);
}
__device__ __forceinline__ float bf16hi_to_f32(uint32_t u) {
    return __builtin_bit_cast(float, u & 0xFFFF0000u);
}
__device__ __forceinline__ uint32_t rne_bf16bits(float x) {   // RNE, low 16 bits valid
    uint32_t b = __builtin_bit_cast(uint32_t, x);
    b += 0x7FFFu + ((b >> 16) & 1u);
    return b >> 16;
}
__device__ __forceinline__ uint32_t pack_bf16x2(float lo, float hi) {
    uint32_t bl = __builtin_bit_cast(uint32_t, lo);
    bl += 0x7FFFu + ((bl >> 16) & 1u);
    uint32_t bh = __builtin_bit_cast(uint32_t, hi);
    bh += 0x7FFFu + ((bh >> 16) & 1u);
    return (bl >> 16) | (bh & 0xFFFF0000u);
}

__device__ __forceinline__ void bfly16_all(float v[16]) {
    #pragma unroll
    for (int bit = 1; bit <= 8; bit <<= 1) {
        #pragma unroll
        for (int m = 0; m < 16; ++m) {
            if (!(m & bit)) {
                float a = v[m], b = v[m | bit];
                v[m] = a + b;
                v[m | bit] = a - b;
            }
        }
    }
}

__device__ __forceinline__ void bfly16_all4(float4 v[16]) {
    #pragma unroll
    for (int bit = 1; bit <= 8; bit <<= 1) {
        #pragma unroll
        for (int m = 0; m < 16; ++m) {
            if (!(m & bit)) {
                float4 a = v[m], b = v[m | bit];
                v[m].x = a.x + b.x; v[m].y = a.y + b.y;
                v[m].z = a.z + b.z; v[m].w = a.w + b.w;
                v[m | bit].x = a.x - b.x; v[m | bit].y = a.y - b.y;
                v[m | bit].z = a.z - b.z; v[m | bit].w = a.w - b.w;
            }
        }
    }
}

// pad: +4 floats every 64 to break the bits{0..4}-only bank aliasing
__device__ __forceinline__ int padA(int l) { return l + ((l >> 6) << 2); }

// ---------------- Pass 1: strides 2^0..2^11 within contiguous 4096-float chunks.
template <bool BF16_OUT>
__global__ __launch_bounds__(256) void wht_pass1(const float* __restrict__ x,
                                                 uint16_t* __restrict__ wsbf,
                                                 float* __restrict__ outf) {
    __shared__ float lds[4096 + 256];
    const int t = threadIdx.x;
    const size_t base = (size_t)blockIdx.x << 12;

    float v[16];
    // Phase A layout: l = 4t + j + 1024*k4 -> in-register strides {1,2,1024,2048}
    #pragma unroll
    for (int k4 = 0; k4 < 4; ++k4) {
        float4 f = reinterpret_cast<const float4*>(x + base)[t + 256 * k4];
        v[k4 * 4 + 0] = f.x; v[k4 * 4 + 1] = f.y;
        v[k4 * 4 + 2] = f.z; v[k4 * 4 + 3] = f.w;
    }
    bfly16_all(v);
    #pragma unroll
    for (int k4 = 0; k4 < 4; ++k4) {
        int l = 4 * t + 1024 * k4;
        *reinterpret_cast<float4*>(&lds[padA(l)]) =
            make_float4(v[k4 * 4 + 0], v[k4 * 4 + 1], v[k4 * 4 + 2], v[k4 * 4 + 3]);
    }
    __syncthreads();

    // Phase B layout: l = (t&3) + 4m + 64*(t>>2) -> strides {4,8,16,32}
    const int cB = (t & 3) + 64 * (t >> 2);
    #pragma unroll
    for (int m = 0; m < 16; ++m) v[m] = lds[padA(cB + 4 * m)];
    bfly16_all(v);
    #pragma unroll
    for (int m = 0; m < 16; ++m) lds[padA(cB + 4 * m)] = v[m];
    __syncthreads();

    // Phase C layout: l = (t&63) + 64m + 1024*(t>>6) -> strides {64,128,256,512}
    const int cC = (t & 63) + 1024 * (t >> 6);
    #pragma unroll
    for (int m = 0; m < 16; ++m) v[m] = lds[padA(cC + 64 * m)];
    bfly16_all(v);

    if (BF16_OUT) {
        // Repack via LDS: linear u16[4096] view -> 2x uint4 coalesced stores.
        __syncthreads();                      // phase-C reads done; safe to overwrite
        uint16_t* lds16 = reinterpret_cast<uint16_t*>(lds);
        #pragma unroll
        for (int m = 0; m < 16; ++m)
            lds16[cC + 64 * m] = (uint16_t)rne_bf16bits(v[m] * 0.015625f);   // 2^-6
        __syncthreads();
        const uint4* l4 = reinterpret_cast<const uint4*>(lds16);
        uint4 a = l4[t];
        uint4 b = l4[t + 256];
        uint4* w4 = reinterpret_cast<uint4*>(wsbf + base);
        w4[t] = a;                            // ws layout: linear p order
        w4[t + 256] = b;
    } else {
        #pragma unroll
        for (int m = 0; m < 16; ++m)
            outf[base + cC + 64 * m] = v[m] * 0.015625f;
    }
}

// ---------------- Pass 2 (bf16 path): WHT-256 over h = idx>>12.
// Tile: 256 h x 128 p. Reads uint4 bf16 from ws (256B/16-lane segments),
// writes f32 to out. LDS: uint4[h][pi8] XOR-swizzled, 64 KB.
__global__ __launch_bounds__(256) void wht_pass2_bf(const uint16_t* __restrict__ ws,
                                                    float* __restrict__ out) {
    __shared__ uint4 lds[256 * 16];                  // 64 KB
    const int t = threadIdx.x;
    const int pi8 = t & 15;                          // 8-float group within 128-p tile
    const int hc = t >> 4;                           // 0..15
    const int pb = blockIdx.x & 31;                  // 32 p-tiles of 128 floats per row
    const int r = blockIdx.x >> 5;                   // row 0..15
    const size_t rbase = ((size_t)r << 20) + (size_t)pb * 128 + (size_t)pi8 * 8;

    float4 va[16], vb[16];

    // Phase A: h = hc + 16m -> element strides 2^16..2^19
    #pragma unroll
    for (int m = 0; m < 16; ++m) {
        uint4 u = *reinterpret_cast<const uint4*>(ws + rbase + (size_t)(hc + 16 * m) * 4096);
        va[m] = make_float4(bf16lo_to_f32(u.x), bf16hi_to_f32(u.x),
                            bf16lo_to_f32(u.y), bf16hi_to_f32(u.y));
        vb[m] = make_float4(bf16lo_to_f32(u.z), bf16hi_to_f32(u.z),
                            bf16lo_to_f32(u.w), bf16hi_to_f32(u.w));
    }
    bfly16_all4(va);
    bfly16_all4(vb);
    #pragma unroll
    for (int m = 0; m < 16; ++m) {
        int h = hc + 16 * m;
        lds[h * 16 + (pi8 ^ (h & 15))] =
            make_uint4(pack_bf16x2(va[m].x, va[m].y), pack_bf16x2(va[m].z, va[m].w),
                       pack_bf16x2(vb[m].x, vb[m].y), pack_bf16x2(vb[m].z, vb[m].w));
    }
    __syncthreads();

    // Phase B: h = hc*16 + m -> element strides 2^12..2^15
    #pragma unroll
    for (int m = 0; m < 16; ++m) {
        int h = hc * 16 + m;
        uint4 u = lds[h * 16 + (pi8 ^ (h & 15))];
        va[m] = make_float4(bf16lo_to_f32(u.x), bf16hi_to_f32(u.x),
                            bf16lo_to_f32(u.y), bf16hi_to_f32(u.y));
        vb[m] = make_float4(bf16lo_to_f32(u.z), bf16hi_to_f32(u.z),
                            bf16lo_to_f32(u.w), bf16hi_to_f32(u.w));
    }
    bfly16_all4(va);
    bfly16_all4(vb);
    #pragma unroll
    for (int m = 0; m < 16; ++m) {
        float* o = out + rbase + (size_t)(hc * 16 + m) * 4096;
        *reinterpret_cast<float4*>(o) =
            make_float4(va[m].x * 0.0625f, va[m].y * 0.0625f,
                        va[m].z * 0.0625f, va[m].w * 0.0625f);   // 2^-4
        *reinterpret_cast<float4*>(o + 4) =
            make_float4(vb[m].x * 0.0625f, vb[m].y * 0.0625f,
                        vb[m].z * 0.0625f, vb[m].w * 0.0625f);
    }
}

// ---------------- Pass 2 (f32 fallback): in-place on out, float4 tile, 64 KB LDS.
__global__ __launch_bounds__(256) void wht_pass2_f32(float* __restrict__ y) {
    __shared__ float4 lds[256 * 16];                 // 64 KB
    const int t = threadIdx.x;
    const int pi4 = t & 15;
    const int hc = t >> 4;
    const int pb = blockIdx.x & 63;
    const int r = blockIdx.x >> 6;
    const size_t rbase = ((size_t)r << 20) + (size_t)pb * 64 + (size_t)pi4 * 4;

    float4 v[16];
    #pragma unroll
    for (int m = 0; m < 16; ++m)
        v[m] = *reinterpret_cast<const float4*>(y + rbase + (size_t)(hc + 16 * m) * 4096);
    bfly16_all4(v);
    #pragma unroll
    for (int m = 0; m < 16; ++m) {
        int h = hc + 16 * m;
        lds[h * 16 + (pi4 ^ (h & 15))] = v[m];
    }
    __syncthreads();
    #pragma unroll
    for (int m = 0; m < 16; ++m) {
        int h = hc * 16 + m;
        v[m] = lds[h * 16 + (pi4 ^ (h & 15))];
    }
    bfly16_all4(v);
    #pragma unroll
    for (int m = 0; m < 16; ++m) {
        float4 o = make_float4(v[m].x * 0.0625f, v[m].y * 0.0625f,
                               v[m].z * 0.0625f, v[m].w * 0.0625f);
        *reinterpret_cast<float4*>(y + rbase + (size_t)(hc * 16 + m) * 4096) = o;
    }
}

extern "C" void kernel_launch(void* const* d_in, const int* in_sizes, int n_in,
                              void* d_out, int out_size, void* d_ws, size_t ws_size,
                              hipStream_t stream) {
    const float* x = (const float*)d_in[0];
    // d_in[1] (signs) and d_in[2] (indxs) are recomputed implicitly -- never read.
    float* out = (float*)d_out;

    const size_t need_ws = (size_t)16 * (1u << 20) * sizeof(uint16_t);  // 32 MB
    if (ws_size >= need_ws) {
        uint16_t* ws = (uint16_t*)d_ws;
        wht_pass1<true><<<4096, 256, 0, stream>>>(x, ws, nullptr);
        wht_pass2_bf<<<512, 256, 0, stream>>>(ws, out);
    } else {
        wht_pass1<false><<<4096, 256, 0, stream>>>(x, nullptr, out);
        wht_pass2_f32<<<1024, 256, 0, stream>>>(out);
    }
}

// Round 8
// 37.476 us; speedup vs baseline: 19.6726x; 1.0747x over previous
//
#include <hip/hip_runtime.h>
#include <stdint.h>

// Full Walsh-Hadamard transform, length 2^20, on 16 rows.
// Scale: inv_sqrt2^20 = 2^-10 exactly; split 2^-6 (pass1) * 2^-4 (pass2).
// Intermediate stored as bf16 in d_ws (halves intermediate traffic).
// This is the best-measured configuration (R3, 37.28 us). Experiments since,
// all reverted: pass1 uint4 store-repack (neutral), nontemporal out-stores
// (neutral), fused producer-consumer single kernel (20x regression: agent-scope
// acquire spin-loads thrash L2), pass2 uint4-wide tile (occupancy loss, -8%).
// Floor arithmetic: 192 MB minimum traffic / ~6.1 TB/s mixed-stream + ~2 us
// 2-dispatch overhead ~= 33-34 us; this kernel sits ~10% above it.
// Fallback to f32 in-place path if ws_size < 32MB.

__device__ __forceinline__ float bf16lo_to_f32(uint32_t u) {
    return __builtin_bit_cast(float, u << 16);
}
__device__ __forceinline__ float bf16hi_to_f32(uint32_t u) {
    return __builtin_bit_cast(float, u & 0xFFFF0000u);
}
__device__ __forceinline__ uint32_t rne_bf16bits(float x) {   // RNE, low 16 bits valid
    uint32_t b = __builtin_bit_cast(uint32_t, x);
    b += 0x7FFFu + ((b >> 16) & 1u);
    return b >> 16;
}
__device__ __forceinline__ uint32_t pack_bf16x2(float lo, float hi) {
    uint32_t bl = __builtin_bit_cast(uint32_t, lo);
    bl += 0x7FFFu + ((bl >> 16) & 1u);
    uint32_t bh = __builtin_bit_cast(uint32_t, hi);
    bh += 0x7FFFu + ((bh >> 16) & 1u);
    return (bl >> 16) | (bh & 0xFFFF0000u);
}

__device__ __forceinline__ void bfly16_all(float v[16]) {
    #pragma unroll
    for (int bit = 1; bit <= 8; bit <<= 1) {
        #pragma unroll
        for (int m = 0; m < 16; ++m) {
            if (!(m & bit)) {
                float a = v[m], b = v[m | bit];
                v[m] = a + b;
                v[m | bit] = a - b;
            }
        }
    }
}

__device__ __forceinline__ void bfly16_all4(float4 v[16]) {
    #pragma unroll
    for (int bit = 1; bit <= 8; bit <<= 1) {
        #pragma unroll
        for (int m = 0; m < 16; ++m) {
            if (!(m & bit)) {
                float4 a = v[m], b = v[m | bit];
                v[m].x = a.x + b.x; v[m].y = a.y + b.y;
                v[m].z = a.z + b.z; v[m].w = a.w + b.w;
                v[m | bit].x = a.x - b.x; v[m | bit].y = a.y - b.y;
                v[m | bit].z = a.z - b.z; v[m | bit].w = a.w - b.w;
            }
        }
    }
}

// pad: +4 floats every 64 to break the bits{0..4}-only bank aliasing
__device__ __forceinline__ int padA(int l) { return l + ((l >> 6) << 2); }

// ---------------- Pass 1: strides 2^0..2^11 within contiguous 4096-float chunks.
template <bool BF16_OUT>
__global__ __launch_bounds__(256) void wht_pass1(const float* __restrict__ x,
                                                 uint16_t* __restrict__ wsbf,
                                                 float* __restrict__ outf) {
    __shared__ float lds[4096 + 256];
    const int t = threadIdx.x;
    const size_t base = (size_t)blockIdx.x << 12;

    float v[16];
    // Phase A layout: l = 4t + j + 1024*k4 -> in-register strides {1,2,1024,2048}
    #pragma unroll
    for (int k4 = 0; k4 < 4; ++k4) {
        float4 f = reinterpret_cast<const float4*>(x + base)[t + 256 * k4];
        v[k4 * 4 + 0] = f.x; v[k4 * 4 + 1] = f.y;
        v[k4 * 4 + 2] = f.z; v[k4 * 4 + 3] = f.w;
    }
    bfly16_all(v);
    #pragma unroll
    for (int k4 = 0; k4 < 4; ++k4) {
        int l = 4 * t + 1024 * k4;
        *reinterpret_cast<float4*>(&lds[padA(l)]) =
            make_float4(v[k4 * 4 + 0], v[k4 * 4 + 1], v[k4 * 4 + 2], v[k4 * 4 + 3]);
    }
    __syncthreads();

    // Phase B layout: l = (t&3) + 4m + 64*(t>>2) -> strides {4,8,16,32}
    const int cB = (t & 3) + 64 * (t >> 2);
    #pragma unroll
    for (int m = 0; m < 16; ++m) v[m] = lds[padA(cB + 4 * m)];
    bfly16_all(v);
    #pragma unroll
    for (int m = 0; m < 16; ++m) lds[padA(cB + 4 * m)] = v[m];
    __syncthreads();

    // Phase C layout: l = (t&63) + 64m + 1024*(t>>6) -> strides {64,128,256,512}
    const int cC = (t & 63) + 1024 * (t >> 6);
    #pragma unroll
    for (int m = 0; m < 16; ++m) v[m] = lds[padA(cC + 64 * m)];
    bfly16_all(v);
    if (BF16_OUT) {
        #pragma unroll
        for (int m = 0; m < 16; ++m)
            wsbf[base + cC + 64 * m] = (uint16_t)rne_bf16bits(v[m] * 0.015625f);   // 2^-6
    } else {
        #pragma unroll
        for (int m = 0; m < 16; ++m)
            outf[base + cC + 64 * m] = v[m] * 0.015625f;
    }
}

// ---------------- Pass 2 (bf16 path): WHT-256 over h = idx>>12.
// Tile: 256 h x 64 p. Reads bf16 from ws, writes f32 to out (no aliasing).
// LDS: uint2[h][pi4] (4 bf16 each), XOR swizzle pi4^(h&15), 32 KB.
__global__ __launch_bounds__(256) void wht_pass2_bf(const uint16_t* __restrict__ ws,
                                                    float* __restrict__ out) {
    __shared__ uint2 lds[256 * 16];                  // 32 KB
    const int t = threadIdx.x;
    const int pi4 = t & 15;
    const int hc = t >> 4;
    const int pb = blockIdx.x & 63;
    const int r = blockIdx.x >> 6;
    const size_t rbase = ((size_t)r << 20) + (size_t)pb * 64 + (size_t)pi4 * 4;

    float4 v[16];

    // Phase A: h = hc + 16m -> element strides 2^16..2^19
    #pragma unroll
    for (int m = 0; m < 16; ++m) {
        uint2 u = *reinterpret_cast<const uint2*>(ws + rbase + (size_t)(hc + 16 * m) * 4096);
        v[m] = make_float4(bf16lo_to_f32(u.x), bf16hi_to_f32(u.x),
                           bf16lo_to_f32(u.y), bf16hi_to_f32(u.y));
    }
    bfly16_all4(v);
    #pragma unroll
    for (int m = 0; m < 16; ++m) {
        int h = hc + 16 * m;
        lds[h * 16 + (pi4 ^ (h & 15))] =
            make_uint2(pack_bf16x2(v[m].x, v[m].y), pack_bf16x2(v[m].z, v[m].w));
    }
    __syncthreads();

    // Phase B: h = hc*16 + m -> element strides 2^12..2^15
    #pragma unroll
    for (int m = 0; m < 16; ++m) {
        int h = hc * 16 + m;
        uint2 u = lds[h * 16 + (pi4 ^ (h & 15))];
        v[m] = make_float4(bf16lo_to_f32(u.x), bf16hi_to_f32(u.x),
                           bf16lo_to_f32(u.y), bf16hi_to_f32(u.y));
    }
    bfly16_all4(v);
    #pragma unroll
    for (int m = 0; m < 16; ++m) {
        float4 o = make_float4(v[m].x * 0.0625f, v[m].y * 0.0625f,
                               v[m].z * 0.0625f, v[m].w * 0.0625f);   // 2^-4
        *reinterpret_cast<float4*>(out + rbase + (size_t)(hc * 16 + m) * 4096) = o;
    }
}

// ---------------- Pass 2 (f32 fallback): in-place on out, float4 tile, 64 KB LDS.
__global__ __launch_bounds__(256) void wht_pass2_f32(float* __restrict__ y) {
    __shared__ float4 lds[256 * 16];                 // 64 KB
    const int t = threadIdx.x;
    const int pi4 = t & 15;
    const int hc = t >> 4;
    const int pb = blockIdx.x & 63;
    const int r = blockIdx.x >> 6;
    const size_t rbase = ((size_t)r << 20) + (size_t)pb * 64 + (size_t)pi4 * 4;

    float4 v[16];
    #pragma unroll
    for (int m = 0; m < 16; ++m)
        v[m] = *reinterpret_cast<const float4*>(y + rbase + (size_t)(hc + 16 * m) * 4096);
    bfly16_all4(v);
    #pragma unroll
    for (int m = 0; m < 16; ++m) {
        int h = hc + 16 * m;
        lds[h * 16 + (pi4 ^ (h & 15))] = v[m];
    }
    __syncthreads();
    #pragma unroll
    for (int m = 0; m < 16; ++m) {
        int h = hc * 16 + m;
        v[m] = lds[h * 16 + (pi4 ^ (h & 15))];
    }
    bfly16_all4(v);
    #pragma unroll
    for (int m = 0; m < 16; ++m) {
        float4 o = make_float4(v[m].x * 0.0625f, v[m].y * 0.0625f,
                               v[m].z * 0.0625f, v[m].w * 0.0625f);
        *reinterpret_cast<float4*>(y + rbase + (size_t)(hc * 16 + m) * 4096) = o;
    }
}

extern "C" void kernel_launch(void* const* d_in, const int* in_sizes, int n_in,
                              void* d_out, int out_size, void* d_ws, size_t ws_size,
                              hipStream_t stream) {
    const float* x = (const float*)d_in[0];
    // d_in[1] (signs) and d_in[2] (indxs) are recomputed implicitly -- never read.
    float* out = (float*)d_out;

    const size_t need_ws = (size_t)16 * (1u << 20) * sizeof(uint16_t);  // 32 MB
    if (ws_size >= need_ws) {
        uint16_t* ws = (uint16_t*)d_ws;
        wht_pass1<true><<<4096, 256, 0, stream>>>(x, ws, nullptr);
        wht_pass2_bf<<<1024, 256, 0, stream>>>(ws, out);
    } else {
        wht_pass1<false><<<4096, 256, 0, stream>>>(x, nullptr, out);
        wht_pass2_f32<<<1024, 256, 0, stream>>>(out);
    }
}